// Round 2
// baseline (35706.354 us; speedup 1.0000x reference)
//
#include <hip/hip_runtime.h>
#include <stdint.h>

#define Tn 512
#define Hn 512
#define Vn 32000
#define KIN 1024
#define G4 2048
#define NBLK 256
#define PHASES 513
#define PSTR 40  // padded LDS row stride (shorts) for proj_gemm

typedef __attribute__((ext_vector_type(8))) short short8;
typedef __attribute__((ext_vector_type(4))) float f32x4;
typedef __attribute__((ext_vector_type(4))) int i32x4;

__device__ __forceinline__ unsigned short f2bf(float v) {
  unsigned int x = __float_as_uint(v);
  return (unsigned short)((x + 0x7fffu + ((x >> 16) & 1u)) >> 16);  // RNE
}
__device__ __forceinline__ float bf2f(unsigned short u) {
  return __uint_as_float(((unsigned int)u) << 16);
}
__device__ __forceinline__ unsigned pollld(const unsigned* p) {
  return __hip_atomic_load(p, __ATOMIC_RELAXED, __HIP_MEMORY_SCOPE_AGENT);
}
__device__ __forceinline__ void flagst(unsigned* p, unsigned v) {
  __hip_atomic_store(p, v, __ATOMIC_RELAXED, __HIP_MEMORY_SCOPE_AGENT);
}

// ---------------- Wout f32 -> transposed bf16 hi/lo [V][H] ----------------
__global__ __launch_bounds__(256) void wout_convert(const float* __restrict__ Wout,
                                                    unsigned short* __restrict__ BhT,
                                                    unsigned short* __restrict__ BlT) {
  __shared__ float ts[64][65];
  const int n0 = blockIdx.x * 64;
  const int k0 = blockIdx.y * 64;
  const int tid = threadIdx.x;
  {
    const int c = tid & 63, rq = tid >> 6;
#pragma unroll
    for (int i = 0; i < 16; ++i) {
      const int k = rq * 16 + i;
      ts[k][c] = Wout[(size_t)(k0 + k) * Vn + (n0 + c)];
    }
  }
  __syncthreads();
  {
    const int nl = tid >> 2;          // 0..63
    const int ks = (tid & 3) * 16;    // 0,16,32,48
    unsigned short hb[16], lb[16];
#pragma unroll
    for (int i = 0; i < 16; ++i) {
      const float v = ts[ks + i][nl];
      const unsigned short h = f2bf(v);
      hb[i] = h;
      lb[i] = f2bf(v - bf2f(h));
    }
    const size_t base = (size_t)(n0 + nl) * Hn + (k0 + ks);
    *(i32x4*)&BhT[base]     = *(const i32x4*)&hb[0];
    *(i32x4*)&BhT[base + 8] = *(const i32x4*)&hb[8];
    *(i32x4*)&BlT[base]     = *(const i32x4*)&lb[0];
    *(i32x4*)&BlT[base + 8] = *(const i32x4*)&lb[8];
  }
}

// ---------------- persistent fused 2-layer LSTM scan ----------------
// 256 blocks x 512 threads (8 waves, 2/SIMD), 1 block/CU (LDS-forced).
// blocks 0..127: layer 0, 128..255: layer 1 (pipelined one step behind).
// 513 phases; per phase: distributed hierarchical device barrier.
__global__ __launch_bounds__(512) void lstm_scan(
    const int* __restrict__ tokens, const float* __restrict__ embed,
    const float* __restrict__ Wg, const float* __restrict__ bg,
    float* __restrict__ hex1, float* __restrict__ hex2,   // [2][16][512] each
    unsigned short* __restrict__ Ah, unsigned short* __restrict__ Al,
    unsigned* __restrict__ arr, unsigned* __restrict__ lvl2) {

  extern __shared__ float smem[];
  float* Wl    = smem;                      // [16][1028]  xor-swizzled along k
  float* xh    = smem + 16 * 1028;          // [16][1028]  xor-swizzled along k
  float* red   = smem + 2 * 16 * 1028;      // [8][16][17]
  float* gates = red + 8 * 272;             // [16][16]
  float* cst   = gates + 256;               // [16][4]
  int*   tokl  = (int*)(cst + 64);          // [16]

  const int tid = threadIdx.x;
  const int bid = blockIdx.x;
  const int layer = bid >> 7;               // 0 or 1
  const int u0 = (bid & 127) * 4;

  // one-time: load W slice (cols = gate*512 + u0 + j), k-swizzled into LDS
  for (int idx = tid; idx < 16 * KIN; idx += 512) {
    const int k = idx >> 4;
    const int c = idx & 15;
    const int col = ((c >> 2) << 9) + u0 + (c & 3);
    const int ch = k >> 2;
    const int phys = ch ^ ((ch >> 3) & 7);
    Wl[c * 1028 + phys * 4 + (k & 3)] =
        Wg[(size_t)layer * KIN * G4 + (size_t)k * G4 + col];
  }
  if (tid < 64) cst[tid] = 0.f;

  float bgv = 0.f;
  if (tid < 256) {
    const int c = tid & 15;
    bgv = bg[layer * G4 + ((c >> 2) << 9) + u0 + (c & 3)];
  }
  __syncthreads();

  const int ksec = tid >> 4;       // 0..31 (32 k each)
  const int bt = (tid >> 2) & 3;   // 4 batches per thread
  const int ct = tid & 3;          // 4 gate-cols per thread
  const int e  = ksec & 7;
  const int ch0 = ksec << 3;       // 8 float4-chunks per ksec
  const int lane = tid & 63;
  const int w = tid >> 6;

  for (int ph = 0; ph < PHASES; ++ph) {
    const int t = (layer == 0) ? ph : ph - 1;
    const bool active = (layer == 0) ? (ph < Tn) : (ph >= 1);
    const unsigned target = (unsigned)(ph + 1);

    if (active && layer == 0 && tid < 16) tokl[tid] = tokens[tid * Tn + t];
    __syncthreads();

    if (active) {
      // stage xh = [x_t(512) || h_prev(512)] for all 16 b, swizzled (plain loads:
      // coherence guaranteed by the acq/rel fences around the device barrier)
      float* hown = (layer == 0 ? hex1 : hex2) + (((t & 1) ^ 1) * (16 * 512));
      const float* hx1 = hex1 + ((t & 1) * (16 * 512));  // h1[t] = layer 1's x
#pragma unroll
      for (int it = 0; it < 8; ++it) {
        const int cid = tid + (it << 9);
        const int b = cid >> 8;
        const int ch = cid & 255;
        const int k = ch << 2;
        float4 v;
        if (layer == 0) {
          v = (k < 512) ? *(const float4*)(embed + (size_t)tokl[b] * Hn + k)
                        : *(const float4*)(hown + b * 512 + (k - 512));
        } else {
          v = (k < 512) ? *(const float4*)(hx1 + b * 512 + k)
                        : *(const float4*)(hown + b * 512 + (k - 512));
        }
        const int phys = ch ^ ((ch >> 3) & 7);
        *(float4*)&xh[b * 1028 + phys * 4] = v;
      }
    }
    __syncthreads();

    if (active) {
      float acc[4][4] = {{0.f,0.f,0.f,0.f},{0.f,0.f,0.f,0.f},
                         {0.f,0.f,0.f,0.f},{0.f,0.f,0.f,0.f}};
#pragma unroll
      for (int it = 0; it < 8; ++it) {
        const int phys4 = ((ch0 | it) ^ e) << 2;
        float4 xv[4], wv[4];
#pragma unroll
        for (int jb = 0; jb < 4; ++jb) xv[jb] = *(const float4*)&xh[(bt * 4 + jb) * 1028 + phys4];
#pragma unroll
        for (int jc = 0; jc < 4; ++jc) wv[jc] = *(const float4*)&Wl[(ct * 4 + jc) * 1028 + phys4];
#pragma unroll
        for (int jb = 0; jb < 4; ++jb)
#pragma unroll
          for (int jc = 0; jc < 4; ++jc) {
            acc[jb][jc] += xv[jb].x * wv[jc].x;
            acc[jb][jc] += xv[jb].y * wv[jc].y;
            acc[jb][jc] += xv[jb].z * wv[jc].z;
            acc[jb][jc] += xv[jb].w * wv[jc].w;
          }
      }
      // in-wave partial reduce over the wave's 4 ksec values (lanes ^16, ^32)
#pragma unroll
      for (int jb = 0; jb < 4; ++jb)
#pragma unroll
        for (int jc = 0; jc < 4; ++jc) {
          float v2 = acc[jb][jc];
          v2 += __shfl_xor(v2, 16, 64);
          v2 += __shfl_xor(v2, 32, 64);
          acc[jb][jc] = v2;
        }
      if (lane < 16) {
#pragma unroll
        for (int jb = 0; jb < 4; ++jb)
#pragma unroll
          for (int jc = 0; jc < 4; ++jc)
            red[w * 272 + (bt * 4 + jb) * 17 + (ct * 4 + jc)] = acc[jb][jc];
      }
    }
    __syncthreads();

    if (active && tid < 256) {
      const int b = tid >> 4, c = tid & 15;
      float s = bgv;
#pragma unroll
      for (int ww = 0; ww < 8; ++ww) s += red[ww * 272 + b * 17 + c];
      gates[b * 16 + c] = s;
    }
    __syncthreads();

    if (active && tid < 64) {
      const int b = tid >> 2, j = tid & 3;
      const float iv = gates[b * 16 + j];
      const float fv = gates[b * 16 + 4 + j];
      const float gv = gates[b * 16 + 8 + j];
      const float ov = gates[b * 16 + 12 + j];
      const float si = 1.f / (1.f + expf(-iv));
      const float sf = 1.f / (1.f + expf(-fv));
      const float tg = tanhf(gv);
      const float so = 1.f / (1.f + expf(-ov));
      const float cn = sf * cst[tid] + si * tg;
      cst[tid] = cn;
      const float hn = so * tanhf(cn);
      float* hdst = (layer == 0 ? hex1 : hex2) + (t & 1) * (16 * 512) + b * 512 + (u0 + j);
      *hdst = hn;  // plain store; flushed by release fence below
      if (layer == 1) {
        const size_t r = (size_t)t * 16 + b;
        const unsigned short hbv = f2bf(hn);
        Ah[r * Hn + u0 + j] = hbv;
        Al[r * Hn + u0 + j] = f2bf(hn - bf2f(hbv));
      }
    }

    // ---- distributed hierarchical device barrier ----
    __syncthreads();                 // all writes issued (vmcnt drained)
    __threadfence();                 // release: wbL2 -> h visible at L3
    if (tid == 0) flagst(&arr[bid * 32], target);
    if (bid < 8) {                   // leader blocks aggregate 32 slots each
      if (tid < 32) {
        const unsigned* slot = arr + (size_t)(bid * 32 + tid) * 32;
        while (pollld(slot) < target) __builtin_amdgcn_s_sleep(2);
      }
      __syncthreads();               // leader observations complete
      if (tid == 0) flagst(&lvl2[bid * 32], target);
    }
    if (tid < 8) {
      const unsigned* slot = lvl2 + (size_t)tid * 32;
      while (pollld(slot) < target) __builtin_amdgcn_s_sleep(2);
    }
    __threadfence();                 // acquire: inv L1/L2 -> fresh h next phase
    __syncthreads();
  }
}

// ---------------- projection GEMM: out[b][t][v] = H2 @ Wout + bout ----------
// split-bf16 x3 MFMA (AhBh + AhBl + AlBh), 128x128 tile, BK=32, 4 waves of 64x64.
// LDS rows padded to 40 shorts (80 B) -> <=2-way bank conflicts on frag reads.
__global__ __launch_bounds__(256) void proj_gemm(
    const unsigned short* __restrict__ Ah_, const unsigned short* __restrict__ Al_,
    const unsigned short* __restrict__ Bh_, const unsigned short* __restrict__ Bl_,
    const float* __restrict__ bout, float* __restrict__ out) {
  __shared__ unsigned short sAh[128 * PSTR], sAl[128 * PSTR], sBh[128 * PSTR], sBl[128 * PSTR];
  const int tid = threadIdx.x;
  const int n0 = blockIdx.x * 128;
  const int m0 = blockIdx.y * 128;
  const int lane = tid & 63, w = tid >> 6;
  const int wm = (w & 1) * 64, wn = (w >> 1) * 64;

  f32x4 acc[4][4];
#pragma unroll
  for (int i = 0; i < 4; ++i)
#pragma unroll
    for (int j = 0; j < 4; ++j) acc[i][j] = (f32x4){0.f, 0.f, 0.f, 0.f};

  for (int kt = 0; kt < 16; ++kt) {
    const int k0 = kt * 32;
    __syncthreads();
#pragma unroll
    for (int i = 0; i < 8; ++i) {
      const int chunk = ((i & 1) << 8) + tid;   // 0..511
      const int mrow = chunk >> 2;
      const int kc = chunk & 3;
      const int tsel = i >> 1;
      const unsigned short* gsrc =
          (tsel == 0) ? Ah_ + (size_t)(m0 + mrow) * Hn + k0 + kc * 8 :
          (tsel == 1) ? Al_ + (size_t)(m0 + mrow) * Hn + k0 + kc * 8 :
          (tsel == 2) ? Bh_ + (size_t)(n0 + mrow) * Hn + k0 + kc * 8 :
                        Bl_ + (size_t)(n0 + mrow) * Hn + k0 + kc * 8;
      unsigned short* ldst = (tsel == 0) ? sAh : (tsel == 1) ? sAl : (tsel == 2) ? sBh : sBl;
      *(i32x4*)&ldst[mrow * PSTR + kc * 8] = *(const i32x4*)gsrc;
    }
    __syncthreads();

    short8 fah[4], fal[4], fbh[4], fbl[4];
    const int rlo = lane & 15, kg = (lane >> 4) * 8;
#pragma unroll
    for (int f = 0; f < 4; ++f) {
      fah[f] = *(const short8*)&sAh[(wm + f * 16 + rlo) * PSTR + kg];
      fal[f] = *(const short8*)&sAl[(wm + f * 16 + rlo) * PSTR + kg];
      fbh[f] = *(const short8*)&sBh[(wn + f * 16 + rlo) * PSTR + kg];
      fbl[f] = *(const short8*)&sBl[(wn + f * 16 + rlo) * PSTR + kg];
    }
#pragma unroll
    for (int i = 0; i < 4; ++i)
#pragma unroll
      for (int j = 0; j < 4; ++j) {
        acc[i][j] = __builtin_amdgcn_mfma_f32_16x16x32_bf16(fah[i], fbh[j], acc[i][j], 0, 0, 0);
        acc[i][j] = __builtin_amdgcn_mfma_f32_16x16x32_bf16(fah[i], fbl[j], acc[i][j], 0, 0, 0);
        acc[i][j] = __builtin_amdgcn_mfma_f32_16x16x32_bf16(fal[i], fbh[j], acc[i][j], 0, 0, 0);
      }
  }

  // epilogue: row r = t*16+b  ->  out[b*T*V + t*V + n], add bout
#pragma unroll
  for (int j = 0; j < 4; ++j) {
    const int n = n0 + wn + j * 16 + (lane & 15);
    const float bv = bout[n];
#pragma unroll
    for (int i = 0; i < 4; ++i) {
#pragma unroll
      for (int r = 0; r < 4; ++r) {
        const int m = m0 + wm + i * 16 + ((lane >> 4) * 4) + r;
        out[(size_t)(m & 15) * ((size_t)Tn * Vn) + (size_t)(m >> 4) * Vn + n] =
            acc[i][j][r] + bv;
      }
    }
  }
}

extern "C" void kernel_launch(void* const* d_in, const int* in_sizes, int n_in,
                              void* d_out, int out_size, void* d_ws, size_t ws_size,
                              hipStream_t stream) {
  const int*   tokens = (const int*)d_in[0];
  const float* embed  = (const float*)d_in[1];
  const float* W      = (const float*)d_in[2];
  const float* bias   = (const float*)d_in[3];
  const float* Wout   = (const float*)d_in[4];
  const float* bout   = (const float*)d_in[5];
  float* out = (float*)d_out;

  char* ws = (char*)d_ws;
  unsigned* arr  = (unsigned*)ws;                      // 256 slots * 128 B
  unsigned* lvl2 = (unsigned*)(ws + 32768);            // 8 slots * 128 B
  float* hex1 = (float*)(ws + 33792);                  // [2][16][512]
  float* hex2 = (float*)(ws + 33792 + 65536);          // [2][16][512]
  unsigned short* Ah  = (unsigned short*)(ws + 164864);
  unsigned short* Al  = Ah + (size_t)8192 * 512;
  unsigned short* BhT = Al + (size_t)8192 * 512;
  unsigned short* BlT = BhT + (size_t)32000 * 512;
  // total ws use: ~82.5 MB

  // zero barrier state + h exchange buffers (fresh every launch -> deterministic)
  hipMemsetAsync(d_ws, 0, 164864, stream);

  wout_convert<<<dim3(500, 8), 256, 0, stream>>>(Wout, BhT, BlT);

  const size_t ldsbytes =
      (size_t)(2 * 16 * 1028 + 8 * 272 + 256 + 64) * 4 + 16 * 4;  // 141632
  (void)hipFuncSetAttribute((const void*)lstm_scan,
                            hipFuncAttributeMaxDynamicSharedMemorySize, (int)ldsbytes);
  lstm_scan<<<NBLK, 512, ldsbytes, stream>>>(tokens, embed, W, bias,
                                             hex1, hex2, Ah, Al, arr, lvl2);

  proj_gemm<<<dim3(250, 64), 256, 0, stream>>>(Ah, Al, BhT, BlT, bout, out);
}

// Round 3
// 5386.430 us; speedup vs baseline: 6.6289x; 6.6289x over previous
//
#include <hip/hip_runtime.h>
#include <stdint.h>

#define Tn 512
#define Hn 512
#define Vn 32000
#define KIN 1024
#define G4 2048
#define NBLK 256
#define PHASES 513
#define PSTR 40        // padded LDS row stride (shorts) for proj_gemm
#define SLOT_STRIDE 2048  // arrival-slot spacing (bytes): one slot per channel-ish

typedef __attribute__((ext_vector_type(8))) short short8;
typedef __attribute__((ext_vector_type(4))) float f32x4;
typedef __attribute__((ext_vector_type(4))) int i32x4;

__device__ __forceinline__ unsigned short f2bf(float v) {
  unsigned int x = __float_as_uint(v);
  return (unsigned short)((x + 0x7fffu + ((x >> 16) & 1u)) >> 16);  // RNE
}
__device__ __forceinline__ float bf2f(unsigned short u) {
  return __uint_as_float(((unsigned int)u) << 16);
}
// relaxed agent-scope (sc1) accesses: served at the coherence point, bypass the
// non-coherent per-XCD L2. No fences anywhere -> no buffer_wbl2/inv storms.
__device__ __forceinline__ unsigned pollld(const unsigned* p) {
  return __hip_atomic_load(p, __ATOMIC_RELAXED, __HIP_MEMORY_SCOPE_AGENT);
}
__device__ __forceinline__ void flagst(unsigned* p, unsigned v) {
  __hip_atomic_store(p, v, __ATOMIC_RELAXED, __HIP_MEMORY_SCOPE_AGENT);
}
__device__ __forceinline__ float aload(const float* p) {
  return __hip_atomic_load(p, __ATOMIC_RELAXED, __HIP_MEMORY_SCOPE_AGENT);
}
__device__ __forceinline__ void astore(float* p, float v) {
  __hip_atomic_store(p, v, __ATOMIC_RELAXED, __HIP_MEMORY_SCOPE_AGENT);
}
__device__ __forceinline__ float4 ald4(const float* p) {
  float4 v;
  v.x = aload(p);
  v.y = aload(p + 1);
  v.z = aload(p + 2);
  v.w = aload(p + 3);
  return v;
}

// ---------------- Wout f32 -> transposed bf16 hi/lo [V][H] ----------------
__global__ __launch_bounds__(256) void wout_convert(const float* __restrict__ Wout,
                                                    unsigned short* __restrict__ BhT,
                                                    unsigned short* __restrict__ BlT) {
  __shared__ float ts[64][65];
  const int n0 = blockIdx.x * 64;
  const int k0 = blockIdx.y * 64;
  const int tid = threadIdx.x;
  {
    const int c = tid & 63, rq = tid >> 6;
#pragma unroll
    for (int i = 0; i < 16; ++i) {
      const int k = rq * 16 + i;
      ts[k][c] = Wout[(size_t)(k0 + k) * Vn + (n0 + c)];
    }
  }
  __syncthreads();
  {
    const int nl = tid >> 2;          // 0..63
    const int ks = (tid & 3) * 16;    // 0,16,32,48
    unsigned short hb[16], lb[16];
#pragma unroll
    for (int i = 0; i < 16; ++i) {
      const float v = ts[ks + i][nl];
      const unsigned short h = f2bf(v);
      hb[i] = h;
      lb[i] = f2bf(v - bf2f(h));
    }
    const size_t base = (size_t)(n0 + nl) * Hn + (k0 + ks);
    *(i32x4*)&BhT[base]     = *(const i32x4*)&hb[0];
    *(i32x4*)&BhT[base + 8] = *(const i32x4*)&hb[8];
    *(i32x4*)&BlT[base]     = *(const i32x4*)&lb[0];
    *(i32x4*)&BlT[base + 8] = *(const i32x4*)&lb[8];
  }
}

// ---------------- persistent fused 2-layer LSTM scan ----------------
// 256 blocks x 512 threads (8 waves, 2/SIMD), 1 block/CU (LDS-forced).
// blocks 0..127: layer 0, 128..255: layer 1 (pipelined one step behind).
// 513 phases; flat fence-free device barrier (monotone slots, sc1 atomics).
__global__ __launch_bounds__(512) void lstm_scan(
    const int* __restrict__ tokens, const float* __restrict__ embed,
    const float* __restrict__ Wg, const float* __restrict__ bg,
    float* __restrict__ hex1, float* __restrict__ hex2,   // [2][16][512] each
    unsigned short* __restrict__ Ah, unsigned short* __restrict__ Al,
    unsigned* __restrict__ arr) {

  extern __shared__ float smem[];
  float* Wl    = smem;                      // [16][1028]  xor-swizzled along k
  float* xh    = smem + 16 * 1028;          // [16][1028]  xor-swizzled along k
  float* red   = smem + 2 * 16 * 1028;      // [8][16][17]
  float* gates = red + 8 * 272;             // [16][16]
  float* cst   = gates + 256;               // [16][4]
  int*   tokl  = (int*)(cst + 64);          // [16]

  const int tid = threadIdx.x;
  const int bid = blockIdx.x;
  const int layer = bid >> 7;               // 0 or 1
  const int u0 = (bid & 127) * 4;

  // one-time: load W slice (cols = gate*512 + u0 + j), k-swizzled into LDS
  for (int idx = tid; idx < 16 * KIN; idx += 512) {
    const int k = idx >> 4;
    const int c = idx & 15;
    const int col = ((c >> 2) << 9) + u0 + (c & 3);
    const int ch = k >> 2;
    const int phys = ch ^ ((ch >> 3) & 7);
    Wl[c * 1028 + phys * 4 + (k & 3)] =
        Wg[(size_t)layer * KIN * G4 + (size_t)k * G4 + col];
  }
  if (tid < 64) cst[tid] = 0.f;

  float bgv = 0.f;
  if (tid < 256) {
    const int c = tid & 15;
    bgv = bg[layer * G4 + ((c >> 2) << 9) + u0 + (c & 3)];
  }
  __syncthreads();

  const int ksec = tid >> 4;       // 0..31 (32 k each)
  const int bt = (tid >> 2) & 3;   // 4 batches per thread
  const int ct = tid & 3;          // 4 gate-cols per thread
  const int e  = ksec & 7;
  const int ch0 = ksec << 3;       // 8 float4-chunks per ksec
  const int lane = tid & 63;
  const int w = tid >> 6;
  unsigned* myslot = (unsigned*)((char*)arr + (size_t)bid * SLOT_STRIDE);
  const unsigned* pollslot =
      (const unsigned*)((const char*)arr + (size_t)(tid & 255) * SLOT_STRIDE);

  for (int ph = 0; ph < PHASES; ++ph) {
    const int t = (layer == 0) ? ph : ph - 1;
    const bool active = (layer == 0) ? (ph < Tn) : (ph >= 1);
    const unsigned target = (unsigned)(ph + 1);

    if (active && layer == 0 && tid < 16) tokl[tid] = tokens[tid * Tn + t];
    __syncthreads();

    if (active) {
      // stage xh = [x_t(512) || h_prev(512)] for all 16 b, swizzled.
      // h halves via sc1 relaxed atomics (coherence point); embed via cached loads.
      float* hown = (layer == 0 ? hex1 : hex2) + (((t & 1) ^ 1) * (16 * 512));
      const float* hx1 = hex1 + ((t & 1) * (16 * 512));  // h1[t] = layer 1's x
#pragma unroll
      for (int it = 0; it < 8; ++it) {
        const int cid = tid + (it << 9);
        const int b = cid >> 8;
        const int ch = cid & 255;
        const int k = ch << 2;
        float4 v;
        if (layer == 0) {
          v = (k < 512) ? *(const float4*)(embed + (size_t)tokl[b] * Hn + k)
                        : ald4(hown + b * 512 + (k - 512));
        } else {
          v = (k < 512) ? ald4(hx1 + b * 512 + k)
                        : ald4(hown + b * 512 + (k - 512));
        }
        const int phys = ch ^ ((ch >> 3) & 7);
        *(float4*)&xh[b * 1028 + phys * 4] = v;
      }
    }
    __syncthreads();

    if (active) {
      float acc[4][4] = {{0.f,0.f,0.f,0.f},{0.f,0.f,0.f,0.f},
                         {0.f,0.f,0.f,0.f},{0.f,0.f,0.f,0.f}};
#pragma unroll
      for (int it = 0; it < 8; ++it) {
        const int phys4 = ((ch0 | it) ^ e) << 2;
        float4 xv[4], wv[4];
#pragma unroll
        for (int jb = 0; jb < 4; ++jb) xv[jb] = *(const float4*)&xh[(bt * 4 + jb) * 1028 + phys4];
#pragma unroll
        for (int jc = 0; jc < 4; ++jc) wv[jc] = *(const float4*)&Wl[(ct * 4 + jc) * 1028 + phys4];
#pragma unroll
        for (int jb = 0; jb < 4; ++jb)
#pragma unroll
          for (int jc = 0; jc < 4; ++jc) {
            acc[jb][jc] += xv[jb].x * wv[jc].x;
            acc[jb][jc] += xv[jb].y * wv[jc].y;
            acc[jb][jc] += xv[jb].z * wv[jc].z;
            acc[jb][jc] += xv[jb].w * wv[jc].w;
          }
      }
      // in-wave partial reduce over the wave's 4 ksec values (lanes ^16, ^32)
#pragma unroll
      for (int jb = 0; jb < 4; ++jb)
#pragma unroll
        for (int jc = 0; jc < 4; ++jc) {
          float v2 = acc[jb][jc];
          v2 += __shfl_xor(v2, 16, 64);
          v2 += __shfl_xor(v2, 32, 64);
          acc[jb][jc] = v2;
        }
      if (lane < 16) {
#pragma unroll
        for (int jb = 0; jb < 4; ++jb)
#pragma unroll
          for (int jc = 0; jc < 4; ++jc)
            red[w * 272 + (bt * 4 + jb) * 17 + (ct * 4 + jc)] = acc[jb][jc];
      }
    }
    __syncthreads();

    if (active && tid < 256) {
      const int b = tid >> 4, c = tid & 15;
      float s = bgv;
#pragma unroll
      for (int ww = 0; ww < 8; ++ww) s += red[ww * 272 + b * 17 + c];
      gates[b * 16 + c] = s;
    }
    __syncthreads();

    if (active && tid < 64) {
      const int b = tid >> 2, j = tid & 3;
      const float iv = gates[b * 16 + j];
      const float fv = gates[b * 16 + 4 + j];
      const float gv = gates[b * 16 + 8 + j];
      const float ov = gates[b * 16 + 12 + j];
      const float si = 1.f / (1.f + expf(-iv));
      const float sf = 1.f / (1.f + expf(-fv));
      const float tg = tanhf(gv);
      const float so = 1.f / (1.f + expf(-ov));
      const float cn = sf * cst[tid] + si * tg;
      cst[tid] = cn;
      const float hn = so * tanhf(cn);
      float* hdst = (layer == 0 ? hex1 : hex2) + (t & 1) * (16 * 512) + b * 512 + (u0 + j);
      astore(hdst, hn);  // sc1 store -> coherence point
      if (layer == 1) {
        const size_t r = (size_t)t * 16 + b;
        const unsigned short hbv = f2bf(hn);
        Ah[r * Hn + u0 + j] = hbv;
        Al[r * Hn + u0 + j] = f2bf(hn - bf2f(hbv));
      }
    }

    // ---- flat fence-free device barrier ----
    // __syncthreads drains each wave's vmcnt -> all sc1 h-stores are committed at
    // the coherence point before tid0 publishes arrival. Pollers' later loads are
    // issued after the flag observation (control dep) -> see fresh h. No fences.
    __syncthreads();
    if (tid == 0) flagst(myslot, target);
    if (tid < 256) {
      while (pollld(pollslot) < target) __builtin_amdgcn_s_sleep(2);
    }
    __syncthreads();
  }
}

// ---------------- projection GEMM: out[b][t][v] = H2 @ Wout + bout ----------
// split-bf16 x3 MFMA (AhBh + AhBl + AlBh), 128x128 tile, BK=32, 4 waves of 64x64.
__global__ __launch_bounds__(256) void proj_gemm(
    const unsigned short* __restrict__ Ah_, const unsigned short* __restrict__ Al_,
    const unsigned short* __restrict__ Bh_, const unsigned short* __restrict__ Bl_,
    const float* __restrict__ bout, float* __restrict__ out) {
  __shared__ unsigned short sAh[128 * PSTR], sAl[128 * PSTR], sBh[128 * PSTR], sBl[128 * PSTR];
  const int tid = threadIdx.x;
  const int n0 = blockIdx.x * 128;
  const int m0 = blockIdx.y * 128;
  const int lane = tid & 63, w = tid >> 6;
  const int wm = (w & 1) * 64, wn = (w >> 1) * 64;

  f32x4 acc[4][4];
#pragma unroll
  for (int i = 0; i < 4; ++i)
#pragma unroll
    for (int j = 0; j < 4; ++j) acc[i][j] = (f32x4){0.f, 0.f, 0.f, 0.f};

  for (int kt = 0; kt < 16; ++kt) {
    const int k0 = kt * 32;
    __syncthreads();
#pragma unroll
    for (int i = 0; i < 8; ++i) {
      const int chunk = ((i & 1) << 8) + tid;   // 0..511
      const int mrow = chunk >> 2;
      const int kc = chunk & 3;
      const int tsel = i >> 1;
      const unsigned short* gsrc =
          (tsel == 0) ? Ah_ + (size_t)(m0 + mrow) * Hn + k0 + kc * 8 :
          (tsel == 1) ? Al_ + (size_t)(m0 + mrow) * Hn + k0 + kc * 8 :
          (tsel == 2) ? Bh_ + (size_t)(n0 + mrow) * Hn + k0 + kc * 8 :
                        Bl_ + (size_t)(n0 + mrow) * Hn + k0 + kc * 8;
      unsigned short* ldst = (tsel == 0) ? sAh : (tsel == 1) ? sAl : (tsel == 2) ? sBh : sBl;
      *(i32x4*)&ldst[mrow * PSTR + kc * 8] = *(const i32x4*)gsrc;
    }
    __syncthreads();

    short8 fah[4], fal[4], fbh[4], fbl[4];
    const int rlo = lane & 15, kg = (lane >> 4) * 8;
#pragma unroll
    for (int f = 0; f < 4; ++f) {
      fah[f] = *(const short8*)&sAh[(wm + f * 16 + rlo) * PSTR + kg];
      fal[f] = *(const short8*)&sAl[(wm + f * 16 + rlo) * PSTR + kg];
      fbh[f] = *(const short8*)&sBh[(wn + f * 16 + rlo) * PSTR + kg];
      fbl[f] = *(const short8*)&sBl[(wn + f * 16 + rlo) * PSTR + kg];
    }
#pragma unroll
    for (int i = 0; i < 4; ++i)
#pragma unroll
      for (int j = 0; j < 4; ++j) {
        acc[i][j] = __builtin_amdgcn_mfma_f32_16x16x32_bf16(fah[i], fbh[j], acc[i][j], 0, 0, 0);
        acc[i][j] = __builtin_amdgcn_mfma_f32_16x16x32_bf16(fah[i], fbl[j], acc[i][j], 0, 0, 0);
        acc[i][j] = __builtin_amdgcn_mfma_f32_16x16x32_bf16(fal[i], fbh[j], acc[i][j], 0, 0, 0);
      }
  }

  // epilogue: row r = t*16+b  ->  out[b*T*V + t*V + n], add bout
#pragma unroll
  for (int j = 0; j < 4; ++j) {
    const int n = n0 + wn + j * 16 + (lane & 15);
    const float bv = bout[n];
#pragma unroll
    for (int i = 0; i < 4; ++i) {
#pragma unroll
      for (int r = 0; r < 4; ++r) {
        const int m = m0 + wm + i * 16 + ((lane >> 4) * 4) + r;
        out[(size_t)(m & 15) * ((size_t)Tn * Vn) + (size_t)(m >> 4) * Vn + n] =
            acc[i][j][r] + bv;
      }
    }
  }
}

extern "C" void kernel_launch(void* const* d_in, const int* in_sizes, int n_in,
                              void* d_out, int out_size, void* d_ws, size_t ws_size,
                              hipStream_t stream) {
  const int*   tokens = (const int*)d_in[0];
  const float* embed  = (const float*)d_in[1];
  const float* W      = (const float*)d_in[2];
  const float* bias   = (const float*)d_in[3];
  const float* Wout   = (const float*)d_in[4];
  const float* bout   = (const float*)d_in[5];
  float* out = (float*)d_out;

  char* ws = (char*)d_ws;
  unsigned* arr = (unsigned*)ws;                       // 256 slots * SLOT_STRIDE
  float* hex1 = (float*)(ws + 256 * SLOT_STRIDE);      // [2][16][512]
  float* hex2 = (float*)(ws + 256 * SLOT_STRIDE + 65536);
  unsigned short* Ah  = (unsigned short*)(ws + 256 * SLOT_STRIDE + 2 * 65536);
  unsigned short* Al  = Ah + (size_t)8192 * 512;
  unsigned short* BhT = Al + (size_t)8192 * 512;
  unsigned short* BlT = BhT + (size_t)32000 * 512;
  // total ws use: ~83 MB

  // zero barrier slots + h exchange buffers (fresh every launch -> deterministic)
  hipMemsetAsync(d_ws, 0, 256 * SLOT_STRIDE + 2 * 65536, stream);

  wout_convert<<<dim3(500, 8), 256, 0, stream>>>(Wout, BhT, BlT);

  const size_t ldsbytes =
      (size_t)(2 * 16 * 1028 + 8 * 272 + 256 + 64) * 4 + 16 * 4;  // 141632
  (void)hipFuncSetAttribute((const void*)lstm_scan,
                            hipFuncAttributeMaxDynamicSharedMemorySize, (int)ldsbytes);
  lstm_scan<<<NBLK, 512, ldsbytes, stream>>>(tokens, embed, W, bias,
                                             hex1, hex2, Ah, Al, arr);

  proj_gemm<<<dim3(250, 64), 256, 0, stream>>>(Ah, Al, BhT, BlT, bout, out);
}

// Round 4
// 4672.727 us; speedup vs baseline: 7.6414x; 1.1527x over previous
//
#include <hip/hip_runtime.h>
#include <stdint.h>

#define Tn 512
#define Hn 512
#define Vn 32000
#define KIN 1024
#define G4 2048
#define NBLK 256
#define PHASES 514        // T + 2 (2-deep pipeline skew)
#define PSTR 40           // padded LDS row stride (shorts) for proj_gemm
#define SLOT_STRIDE 2048  // arrival-slot spacing (bytes)

typedef __attribute__((ext_vector_type(8))) short short8;
typedef __attribute__((ext_vector_type(4))) float f32x4;
typedef __attribute__((ext_vector_type(4))) int i32x4;

__device__ __forceinline__ unsigned short f2bf(float v) {
  unsigned int x = __float_as_uint(v);
  return (unsigned short)((x + 0x7fffu + ((x >> 16) & 1u)) >> 16);  // RNE
}
__device__ __forceinline__ float bf2f(unsigned short u) {
  return __uint_as_float(((unsigned int)u) << 16);
}
// relaxed agent-scope (sc1): served at coherence point, bypass non-coherent L2.
__device__ __forceinline__ unsigned pollld(const unsigned* p) {
  return __hip_atomic_load(p, __ATOMIC_RELAXED, __HIP_MEMORY_SCOPE_AGENT);
}
__device__ __forceinline__ void flagst(unsigned* p, unsigned v) {
  __hip_atomic_store(p, v, __ATOMIC_RELAXED, __HIP_MEMORY_SCOPE_AGENT);
}
__device__ __forceinline__ void astore(float* p, float v) {
  __hip_atomic_store(p, v, __ATOMIC_RELAXED, __HIP_MEMORY_SCOPE_AGENT);
}

// 4x coherent dwordx4 loads (sc1) batched under one vmcnt; consumers are
// ds_writes (memory ops) -> ordered by the "memory" clobber.
__device__ __forceinline__ void stage_sc1(const float* src, float* xh, int row,
                                          int chbase, int e) {
  f32x4 v0, v1, v2, v3;
  asm volatile(
      "global_load_dwordx4 %0, %4, off sc1\n\t"
      "global_load_dwordx4 %1, %5, off sc1\n\t"
      "global_load_dwordx4 %2, %6, off sc1\n\t"
      "global_load_dwordx4 %3, %7, off sc1\n\t"
      "s_waitcnt vmcnt(0)"
      : "=&v"(v0), "=&v"(v1), "=&v"(v2), "=&v"(v3)
      : "v"(src), "v"(src + 4), "v"(src + 8), "v"(src + 12)
      : "memory");
  *(f32x4*)&xh[row * 1028 + ((chbase + 0) ^ e) * 4] = v0;
  *(f32x4*)&xh[row * 1028 + ((chbase + 1) ^ e) * 4] = v1;
  *(f32x4*)&xh[row * 1028 + ((chbase + 2) ^ e) * 4] = v2;
  *(f32x4*)&xh[row * 1028 + ((chbase + 3) ^ e) * 4] = v3;
}
__device__ __forceinline__ void stage_plain(const float* src, float* xh, int row,
                                            int chbase, int e) {
  f32x4 v0 = *(const f32x4*)src;
  f32x4 v1 = *(const f32x4*)(src + 4);
  f32x4 v2 = *(const f32x4*)(src + 8);
  f32x4 v3 = *(const f32x4*)(src + 12);
  *(f32x4*)&xh[row * 1028 + ((chbase + 0) ^ e) * 4] = v0;
  *(f32x4*)&xh[row * 1028 + ((chbase + 1) ^ e) * 4] = v1;
  *(f32x4*)&xh[row * 1028 + ((chbase + 2) ^ e) * 4] = v2;
  *(f32x4*)&xh[row * 1028 + ((chbase + 3) ^ e) * 4] = v3;
}

// one K=512 partial dot: 32 ksec x (4 batches x 4 cols)/thread, shfl-reduce
// the wave's 4 ksec, write 8 wave-partials to red[8][16][17].
__device__ __forceinline__ void part_dot(const float* __restrict__ Wl,
                                         const float* __restrict__ xh,
                                         int partch, int ksec, int bt, int ct,
                                         int lane, int w, float* __restrict__ red) {
  float acc[4][4] = {{0.f,0.f,0.f,0.f},{0.f,0.f,0.f,0.f},
                     {0.f,0.f,0.f,0.f},{0.f,0.f,0.f,0.f}};
#pragma unroll
  for (int it = 0; it < 4; ++it) {
    const int ch = partch + (ksec << 2) + it;
    const int phys4 = (ch ^ ((ch >> 3) & 7)) << 2;
    f32x4 xv[4], wv[4];
#pragma unroll
    for (int jb = 0; jb < 4; ++jb) xv[jb] = *(const f32x4*)&xh[(bt * 4 + jb) * 1028 + phys4];
#pragma unroll
    for (int jc = 0; jc < 4; ++jc) wv[jc] = *(const f32x4*)&Wl[(ct * 4 + jc) * 1028 + phys4];
#pragma unroll
    for (int jb = 0; jb < 4; ++jb)
#pragma unroll
      for (int jc = 0; jc < 4; ++jc) {
        acc[jb][jc] += xv[jb][0] * wv[jc][0];
        acc[jb][jc] += xv[jb][1] * wv[jc][1];
        acc[jb][jc] += xv[jb][2] * wv[jc][2];
        acc[jb][jc] += xv[jb][3] * wv[jc][3];
      }
  }
#pragma unroll
  for (int jb = 0; jb < 4; ++jb)
#pragma unroll
    for (int jc = 0; jc < 4; ++jc) {
      float v2 = acc[jb][jc];
      v2 += __shfl_xor(v2, 16, 64);
      v2 += __shfl_xor(v2, 32, 64);
      acc[jb][jc] = v2;
    }
  if (lane < 16) {
#pragma unroll
    for (int jb = 0; jb < 4; ++jb)
#pragma unroll
      for (int jc = 0; jc < 4; ++jc)
        red[w * 272 + (bt * 4 + jb) * 17 + (ct * 4 + jc)] = acc[jb][jc];
  }
}

// ---------------- Wout f32 -> transposed bf16 hi/lo [V][H] ----------------
__global__ __launch_bounds__(256) void wout_convert(const float* __restrict__ Wout,
                                                    unsigned short* __restrict__ BhT,
                                                    unsigned short* __restrict__ BlT) {
  __shared__ float ts[64][65];
  const int n0 = blockIdx.x * 64;
  const int k0 = blockIdx.y * 64;
  const int tid = threadIdx.x;
  {
    const int c = tid & 63, rq = tid >> 6;
#pragma unroll
    for (int i = 0; i < 16; ++i) {
      const int k = rq * 16 + i;
      ts[k][c] = Wout[(size_t)(k0 + k) * Vn + (n0 + c)];
    }
  }
  __syncthreads();
  {
    const int nl = tid >> 2;
    const int ks = (tid & 3) * 16;
    unsigned short hb[16], lb[16];
#pragma unroll
    for (int i = 0; i < 16; ++i) {
      const float v = ts[ks + i][nl];
      const unsigned short h = f2bf(v);
      hb[i] = h;
      lb[i] = f2bf(v - bf2f(h));
    }
    const size_t base = (size_t)(n0 + nl) * Hn + (k0 + ks);
    *(i32x4*)&BhT[base]     = *(const i32x4*)&hb[0];
    *(i32x4*)&BhT[base + 8] = *(const i32x4*)&hb[8];
    *(i32x4*)&BlT[base]     = *(const i32x4*)&lb[0];
    *(i32x4*)&BlT[base + 8] = *(const i32x4*)&lb[8];
  }
}

// ---------------- persistent fused 2-layer LSTM scan (2-deep skew) ----------
// 256 blocks x 512 threads, 1 block/CU. blocks 0..127: layer 0 (step t = ph),
// 128..255: layer 1 (step t = ph-2). Per phase: critical h-part (K=512) before
// barrier arrival; x-part (K=512) for the NEXT step after arrival (overlaps the
// poll wait). hex1 (h1) triple-buffered; hex2 (h2) double-buffered.
__global__ __launch_bounds__(512) void lstm_scan(
    const int* __restrict__ tokens, const float* __restrict__ embed,
    const float* __restrict__ Wg, const float* __restrict__ bg,
    float* __restrict__ hex1, float* __restrict__ hex2,
    unsigned short* __restrict__ Ah, unsigned short* __restrict__ Al,
    unsigned* __restrict__ arr) {

  extern __shared__ float smem[];
  float* Wl    = smem;              // [16][1028] xor-swizzled (k rows 0..1023)
  float* xh    = smem + 16448;      // [16][1028] x half: ch 0..127, h half: 128..255
  float* red_h = smem + 32896;      // [8][272]
  float* red_x = red_h + 2176;      // [8][272]
  float* cst   = red_x + 2176;      // [64]

  const int tid = threadIdx.x;
  const int bid = blockIdx.x;
  const int layer = bid >> 7;
  const int u0 = (bid & 127) * 4;

  // one-time: W slice (cols = gate*512 + u0 + j) k-swizzled into LDS
  for (int idx = tid; idx < 16 * KIN; idx += 512) {
    const int k = idx >> 4;
    const int c = idx & 15;
    const int col = ((c >> 2) << 9) + u0 + (c & 3);
    const int ch = k >> 2;
    const int phys = ch ^ ((ch >> 3) & 7);
    Wl[c * 1028 + phys * 4 + (k & 3)] =
        Wg[(size_t)layer * KIN * G4 + (size_t)k * G4 + col];
  }
  if (tid < 64) cst[tid] = 0.f;

  float bb[4] = {0.f, 0.f, 0.f, 0.f};
  if (tid < 64) {
    const int j = tid & 3;
#pragma unroll
    for (int g = 0; g < 4; ++g) bb[g] = bg[layer * G4 + g * 512 + u0 + j];
  }

  const int ksec = tid >> 4;
  const int bt = (tid >> 2) & 3;
  const int ct = tid & 3;
  const int lane = tid & 63;
  const int w = tid >> 6;
  const int srow = tid >> 5;        // staging row 0..15
  const int scc = tid & 31;         // staging chunk group (4 chunks each)
  const int e = (tid >> 1) & 7;     // swizzle key for this thread's 4 chunks
  unsigned* myslot = (unsigned*)((char*)arr + (size_t)bid * SLOT_STRIDE);
  const unsigned* pollslot =
      (const unsigned*)((const char*)arr + (size_t)(tid & 255) * SLOT_STRIDE);

  __syncthreads();

  // prologue: L0 precomputes x-part (embed) for t=0
  if (layer == 0) {
    const int tok = tokens[srow * Tn];
    stage_plain(embed + (size_t)tok * Hn + scc * 16, xh, srow, scc * 4, e);
  }
  __syncthreads();
  if (layer == 0) part_dot(Wl, xh, 0, ksec, bt, ct, lane, w, red_x);
  __syncthreads();

  int s1w = 0, s1r = 2;  // hex1 slots: write = ph mod 3, read = (ph-1) mod 3

  for (int ph = 0; ph < PHASES; ++ph) {
    const unsigned target = (unsigned)(ph + 1);
    const bool act0 = (layer == 0) ? (ph < Tn) : (ph >= 2);
    const int t = (layer == 0) ? ph : ph - 2;

    // --- critical: stage h-half (sc1 dwordx4) ---
    if (act0) {
      const float* hsrc = (layer == 0)
          ? hex1 + s1r * (16 * 512)
          : hex2 + ((ph - 3) & 1) * (16 * 512);
      stage_sc1(hsrc + srow * 512 + scc * 16, xh, srow, 128 + scc * 4, e);
    }
    __syncthreads();

    // --- critical: h-part dot (K=512) ---
    if (act0) part_dot(Wl, xh, 128, ksec, bt, ct, lane, w, red_h);
    __syncthreads();

    // --- combine + activations + h store (64 threads) ---
    if (act0 && tid < 64) {
      const int b = tid >> 2, j = tid & 3;
      float g4[4];
#pragma unroll
      for (int g = 0; g < 4; ++g) {
        const int c = g * 4 + j;
        float s = bb[g];
#pragma unroll
        for (int ww = 0; ww < 8; ++ww)
          s += red_h[ww * 272 + b * 17 + c] + red_x[ww * 272 + b * 17 + c];
        g4[g] = s;
      }
      const float si = 1.f / (1.f + expf(-g4[0]));
      const float sf = 1.f / (1.f + expf(-g4[1]));
      const float tg = tanhf(g4[2]);
      const float so = 1.f / (1.f + expf(-g4[3]));
      const float cn = sf * cst[tid] + si * tg;
      cst[tid] = cn;
      const float hn = so * tanhf(cn);
      float* hdst = (layer == 0)
          ? hex1 + s1w * (16 * 512) + b * 512 + (u0 + j)
          : hex2 + ((ph - 2) & 1) * (16 * 512) + b * 512 + (u0 + j);
      astore(hdst, hn);
      if (layer == 1) {
        const size_t r = (size_t)t * 16 + b;
        const unsigned short hbv = f2bf(hn);
        Ah[r * Hn + u0 + j] = hbv;
        Al[r * Hn + u0 + j] = f2bf(hn - bf2f(hbv));
      }
    }
    __syncthreads();  // drains h stores (vmcnt) block-wide

    if (tid == 0) flagst(myslot, target);

    // --- wait-slot precompute: x-part for the next step ---
    const bool pre = (layer == 0) ? (ph + 1 < Tn) : (ph >= 1 && ph <= Tn);
    if (pre) {
      if (layer == 0) {
        const int tok = tokens[srow * Tn + (ph + 1)];
        stage_plain(embed + (size_t)tok * Hn + scc * 16, xh, srow, scc * 4, e);
      } else {
        const float* xsrc = hex1 + s1r * (16 * 512);  // h1[ph-1]
        stage_sc1(xsrc + srow * 512 + scc * 16, xh, srow, scc * 4, e);
      }
    }
    __syncthreads();
    if (pre) part_dot(Wl, xh, 0, ksec, bt, ct, lane, w, red_x);

    // --- poll (overlapped with the precompute above) ---
    if (tid < 256) {
      while (pollld(pollslot) < target) __builtin_amdgcn_s_sleep(2);
    }
    __syncthreads();

    s1r = s1w;
    s1w = (s1w == 2) ? 0 : s1w + 1;
  }
}

// ---------------- projection GEMM: out[b][t][v] = H2 @ Wout + bout ----------
__global__ __launch_bounds__(256) void proj_gemm(
    const unsigned short* __restrict__ Ah_, const unsigned short* __restrict__ Al_,
    const unsigned short* __restrict__ Bh_, const unsigned short* __restrict__ Bl_,
    const float* __restrict__ bout, float* __restrict__ out) {
  __shared__ unsigned short sAh[128 * PSTR], sAl[128 * PSTR], sBh[128 * PSTR], sBl[128 * PSTR];
  const int tid = threadIdx.x;
  const int n0 = blockIdx.x * 128;
  const int m0 = blockIdx.y * 128;
  const int lane = tid & 63, w = tid >> 6;
  const int wm = (w & 1) * 64, wn = (w >> 1) * 64;

  f32x4 acc[4][4];
#pragma unroll
  for (int i = 0; i < 4; ++i)
#pragma unroll
    for (int j = 0; j < 4; ++j) acc[i][j] = (f32x4){0.f, 0.f, 0.f, 0.f};

  for (int kt = 0; kt < 16; ++kt) {
    const int k0 = kt * 32;
    __syncthreads();
#pragma unroll
    for (int i = 0; i < 8; ++i) {
      const int chunk = ((i & 1) << 8) + tid;
      const int mrow = chunk >> 2;
      const int kc = chunk & 3;
      const int tsel = i >> 1;
      const unsigned short* gsrc =
          (tsel == 0) ? Ah_ + (size_t)(m0 + mrow) * Hn + k0 + kc * 8 :
          (tsel == 1) ? Al_ + (size_t)(m0 + mrow) * Hn + k0 + kc * 8 :
          (tsel == 2) ? Bh_ + (size_t)(n0 + mrow) * Hn + k0 + kc * 8 :
                        Bl_ + (size_t)(n0 + mrow) * Hn + k0 + kc * 8;
      unsigned short* ldst = (tsel == 0) ? sAh : (tsel == 1) ? sAl : (tsel == 2) ? sBh : sBl;
      *(i32x4*)&ldst[mrow * PSTR + kc * 8] = *(const i32x4*)gsrc;
    }
    __syncthreads();

    short8 fah[4], fal[4], fbh[4], fbl[4];
    const int rlo = lane & 15, kg = (lane >> 4) * 8;
#pragma unroll
    for (int f = 0; f < 4; ++f) {
      fah[f] = *(const short8*)&sAh[(wm + f * 16 + rlo) * PSTR + kg];
      fal[f] = *(const short8*)&sAl[(wm + f * 16 + rlo) * PSTR + kg];
      fbh[f] = *(const short8*)&sBh[(wn + f * 16 + rlo) * PSTR + kg];
      fbl[f] = *(const short8*)&sBl[(wn + f * 16 + rlo) * PSTR + kg];
    }
#pragma unroll
    for (int i = 0; i < 4; ++i)
#pragma unroll
      for (int j = 0; j < 4; ++j) {
        acc[i][j] = __builtin_amdgcn_mfma_f32_16x16x32_bf16(fah[i], fbh[j], acc[i][j], 0, 0, 0);
        acc[i][j] = __builtin_amdgcn_mfma_f32_16x16x32_bf16(fah[i], fbl[j], acc[i][j], 0, 0, 0);
        acc[i][j] = __builtin_amdgcn_mfma_f32_16x16x32_bf16(fal[i], fbh[j], acc[i][j], 0, 0, 0);
      }
  }

#pragma unroll
  for (int j = 0; j < 4; ++j) {
    const int n = n0 + wn + j * 16 + (lane & 15);
    const float bv = bout[n];
#pragma unroll
    for (int i = 0; i < 4; ++i) {
#pragma unroll
      for (int r = 0; r < 4; ++r) {
        const int m = m0 + wm + i * 16 + ((lane >> 4) * 4) + r;
        out[(size_t)(m & 15) * ((size_t)Tn * Vn) + (size_t)(m >> 4) * Vn + n] =
            acc[i][j][r] + bv;
      }
    }
  }
}

extern "C" void kernel_launch(void* const* d_in, const int* in_sizes, int n_in,
                              void* d_out, int out_size, void* d_ws, size_t ws_size,
                              hipStream_t stream) {
  const int*   tokens = (const int*)d_in[0];
  const float* embed  = (const float*)d_in[1];
  const float* W      = (const float*)d_in[2];
  const float* bias   = (const float*)d_in[3];
  const float* Wout   = (const float*)d_in[4];
  const float* bout   = (const float*)d_in[5];
  float* out = (float*)d_out;

  char* ws = (char*)d_ws;
  unsigned* arr = (unsigned*)ws;                            // 256 * 2048 B
  float* hex1 = (float*)(ws + 524288);                      // 3 slots * 32 KB
  float* hex2 = (float*)(ws + 524288 + 98304);              // 2 slots * 32 KB
  unsigned short* Ah  = (unsigned short*)(ws + 688128);
  unsigned short* Al  = Ah + (size_t)8192 * 512;
  unsigned short* BhT = Al + (size_t)8192 * 512;
  unsigned short* BlT = BhT + (size_t)32000 * 512;

  // zero barrier slots + h exchange buffers (fresh every launch)
  hipMemsetAsync(d_ws, 0, 688128, stream);

  wout_convert<<<dim3(500, 8), 256, 0, stream>>>(Wout, BhT, BlT);

  const size_t ldsbytes = (size_t)(16448 * 2 + 2176 * 2 + 64) * 4;  // 149248
  (void)hipFuncSetAttribute((const void*)lstm_scan,
                            hipFuncAttributeMaxDynamicSharedMemorySize, (int)ldsbytes);
  lstm_scan<<<NBLK, 512, ldsbytes, stream>>>(tokens, embed, W, bias,
                                             hex1, hex2, Ah, Al, arr);

  proj_gemm<<<dim3(250, 64), 256, 0, stream>>>(Ah, Al, BhT, BlT, bout, out);
}

// Round 5
// 3311.724 us; speedup vs baseline: 10.7818x; 1.4110x over previous
//
#include <hip/hip_runtime.h>
#include <stdint.h>

#define Tn 512
#define Hn 512
#define Vn 32000
#define KIN 1024
#define G4 2048
#define NBLK 256
#define PHASES 513
#define PSTR 40           // padded LDS row stride (shorts) for proj_gemm
#define XSTR 1032         // padded LDS row stride (shorts) for scan tiles
#define SLOT_STRIDE 2048  // barrier arrival-slot spacing (bytes)

typedef __attribute__((ext_vector_type(8))) short short8;
typedef __attribute__((ext_vector_type(4))) float f32x4;
typedef __attribute__((ext_vector_type(4))) int i32x4;
typedef __attribute__((ext_vector_type(4))) unsigned u32x4;

__device__ __forceinline__ unsigned short f2bf(float v) {
  unsigned int x = __float_as_uint(v);
  return (unsigned short)((x + 0x7fffu + ((x >> 16) & 1u)) >> 16);  // RNE
}
__device__ __forceinline__ float bf2f(unsigned short u) {
  return __uint_as_float(((unsigned int)u) << 16);
}
// relaxed agent-scope (sc1): served at coherence point, bypass non-coherent L2.
// NO fences anywhere (round-2 lesson: per-thread __threadfence = wbL2 storm).
__device__ __forceinline__ unsigned pollld(const unsigned* p) {
  return __hip_atomic_load(p, __ATOMIC_RELAXED, __HIP_MEMORY_SCOPE_AGENT);
}
__device__ __forceinline__ void flagst(unsigned* p, unsigned v) {
  __hip_atomic_store(p, v, __ATOMIC_RELAXED, __HIP_MEMORY_SCOPE_AGENT);
}

// Stage 16 packed (hi16|lo16) h values from the coherence point into the bf16
// hi/lo LDS tiles. 4 sc1 dwordx4 in flight under one vmcnt; LDS-write
// consumers are memory ops -> ordered by the "memory" clobber.
__device__ __forceinline__ void stage_unpack_sc1(const unsigned* src,
                                                 unsigned short* Xh,
                                                 unsigned short* Xl, int off) {
  u32x4 a, b, c, d;
  asm volatile(
      "global_load_dwordx4 %0, %4, off sc1\n\t"
      "global_load_dwordx4 %1, %5, off sc1\n\t"
      "global_load_dwordx4 %2, %6, off sc1\n\t"
      "global_load_dwordx4 %3, %7, off sc1\n\t"
      "s_waitcnt vmcnt(0)"
      : "=&v"(a), "=&v"(b), "=&v"(c), "=&v"(d)
      : "v"(src), "v"(src + 4), "v"(src + 8), "v"(src + 12)
      : "memory");
  unsigned u[16];
#pragma unroll
  for (int i = 0; i < 4; ++i) {
    u[i] = a[i]; u[4 + i] = b[i]; u[8 + i] = c[i]; u[12 + i] = d[i];
  }
  unsigned hw[8], lw[8];
#pragma unroll
  for (int j = 0; j < 8; ++j) {
    const unsigned e0 = u[2 * j], e1 = u[2 * j + 1];
    hw[j] = (e0 >> 16) | (e1 & 0xffff0000u);
    lw[j] = (e0 & 0xffffu) | (e1 << 16);
  }
  *(u32x4*)&Xh[off]     = *(const u32x4*)&hw[0];
  *(u32x4*)&Xh[off + 8] = *(const u32x4*)&hw[4];
  *(u32x4*)&Xl[off]     = *(const u32x4*)&lw[0];
  *(u32x4*)&Xl[off + 8] = *(const u32x4*)&lw[4];
}

// Stage 16 f32 (embed row segment) -> bf16 hi/lo LDS tiles (plain cached loads).
__device__ __forceinline__ void stage_f32(const float* src, unsigned short* Xh,
                                          unsigned short* Xl, int off) {
  const f32x4 v0 = *(const f32x4*)src;
  const f32x4 v1 = *(const f32x4*)(src + 4);
  const f32x4 v2 = *(const f32x4*)(src + 8);
  const f32x4 v3 = *(const f32x4*)(src + 12);
  unsigned short h16[16], l16[16];
#pragma unroll
  for (int i = 0; i < 4; ++i) {
    float x;
    x = v0[i]; h16[i]      = f2bf(x); l16[i]      = f2bf(x - bf2f(h16[i]));
    x = v1[i]; h16[4 + i]  = f2bf(x); l16[4 + i]  = f2bf(x - bf2f(h16[4 + i]));
    x = v2[i]; h16[8 + i]  = f2bf(x); l16[8 + i]  = f2bf(x - bf2f(h16[8 + i]));
    x = v3[i]; h16[12 + i] = f2bf(x); l16[12 + i] = f2bf(x - bf2f(h16[12 + i]));
  }
  *(u32x4*)&Xh[off]     = *(const u32x4*)&h16[0];
  *(u32x4*)&Xh[off + 8] = *(const u32x4*)&h16[8];
  *(u32x4*)&Xl[off]     = *(const u32x4*)&l16[0];
  *(u32x4*)&Xl[off + 8] = *(const u32x4*)&l16[8];
}

// ---------------- Wout f32 -> transposed bf16 hi/lo [V][H] ----------------
__global__ __launch_bounds__(256) void wout_convert(const float* __restrict__ Wout,
                                                    unsigned short* __restrict__ BhT,
                                                    unsigned short* __restrict__ BlT) {
  __shared__ float ts[64][65];
  const int n0 = blockIdx.x * 64;
  const int k0 = blockIdx.y * 64;
  const int tid = threadIdx.x;
  {
    const int c = tid & 63, rq = tid >> 6;
#pragma unroll
    for (int i = 0; i < 16; ++i) {
      const int k = rq * 16 + i;
      ts[k][c] = Wout[(size_t)(k0 + k) * Vn + (n0 + c)];
    }
  }
  __syncthreads();
  {
    const int nl = tid >> 2;
    const int ks = (tid & 3) * 16;
    unsigned short hb[16], lb[16];
#pragma unroll
    for (int i = 0; i < 16; ++i) {
      const float v = ts[ks + i][nl];
      const unsigned short h = f2bf(v);
      hb[i] = h;
      lb[i] = f2bf(v - bf2f(h));
    }
    const size_t base = (size_t)(n0 + nl) * Hn + (k0 + ks);
    *(i32x4*)&BhT[base]     = *(const i32x4*)&hb[0];
    *(i32x4*)&BhT[base + 8] = *(const i32x4*)&hb[8];
    *(i32x4*)&BlT[base]     = *(const i32x4*)&lb[0];
    *(i32x4*)&BlT[base + 8] = *(const i32x4*)&lb[8];
  }
}

// ---------------- persistent fused 2-layer LSTM scan (MFMA core) -----------
// 256 blocks x 512 threads, 1 block/CU (LDS 142 KB). blocks 0..127: layer 0
// (t = ph), 128..255: layer 1 (t = ph-1). Per block: 16x16 gate tile via
// mfma 16x16x32 split-bf16 x3, K=1024 sliced 128/wave, f32 partials reduced
// in LDS. h exchanged cross-XCD as packed u32 (bf16 hi|lo) via sc1 atomics.
__global__ __launch_bounds__(512) void lstm_scan(
    const int* __restrict__ tokens, const float* __restrict__ embed,
    const float* __restrict__ Wg, const float* __restrict__ bg,
    unsigned* __restrict__ hex1, unsigned* __restrict__ hex2,  // [2][16][512] u32
    unsigned short* __restrict__ Ah, unsigned short* __restrict__ Al,
    unsigned* __restrict__ arr) {

  extern __shared__ char smembytes[];
  unsigned short* Wh  = (unsigned short*)smembytes;  // [16][XSTR] bf16 hi
  unsigned short* Wlo = Wh + 16 * XSTR;              // [16][XSTR] bf16 lo
  unsigned short* Xh  = Wlo + 16 * XSTR;             // [16][XSTR] xh hi
  unsigned short* Xl  = Xh + 16 * XSTR;              // [16][XSTR] xh lo
  float* red   = (float*)(Xl + 16 * XSTR);           // [8][272]
  float* gates = red + 8 * 272;                      // [256]
  float* cst   = gates + 256;                        // [64]

  const int tid = threadIdx.x;
  const int bid = blockIdx.x;
  const int layer = bid >> 7;
  const int u0 = (bid & 127) * 4;

  // one-time: W slice (cols = gate*512 + u0 + j) -> bf16 hi/lo in LDS
  for (int idx = tid; idx < 16 * KIN; idx += 512) {
    const int k = idx >> 4;
    const int c = idx & 15;
    const int col = ((c >> 2) << 9) + u0 + (c & 3);
    const float wv = Wg[(size_t)layer * KIN * G4 + (size_t)k * G4 + col];
    const unsigned short h = f2bf(wv);
    Wh[c * XSTR + k] = h;
    Wlo[c * XSTR + k] = f2bf(wv - bf2f(h));
  }
  if (tid < 64) cst[tid] = 0.f;

  float bb0 = 0.f, bb1 = 0.f, bb2 = 0.f, bb3 = 0.f;
  if (tid < 64) {
    const int j = tid & 3;
    bb0 = bg[layer * G4 + 0 * 512 + u0 + j];
    bb1 = bg[layer * G4 + 1 * 512 + u0 + j];
    bb2 = bg[layer * G4 + 2 * 512 + u0 + j];
    bb3 = bg[layer * G4 + 3 * 512 + u0 + j];
  }

  const int lane = tid & 63;
  const int w = tid >> 6;          // wave 0..7: K-slice [w*128, w*128+128)
  const int srow = tid >> 5;       // staging row 0..15
  const int kseg = (tid & 31) * 16;  // staging k offset (16 values/thread)
  const int m = lane & 15;         // A row (batch) & B row (gate col) selector
  const int g8 = (lane >> 4) * 8;  // k-octet within the 32-k MFMA window
  unsigned* myslot = (unsigned*)((char*)arr + (size_t)bid * SLOT_STRIDE);
  const unsigned* pollslot =
      (const unsigned*)((const char*)arr + (size_t)(tid & 255) * SLOT_STRIDE);

  __syncthreads();

  // prologue: L0 stages x(t=0) = embed rows
  if (layer == 0) {
    const int tok = tokens[srow * Tn + 0];
    stage_f32(embed + (size_t)tok * Hn + kseg, Xh, Xl, srow * XSTR + kseg);
  }

  for (int ph = 0; ph < PHASES; ++ph) {
    const unsigned target = (unsigned)(ph + 1);
    const bool act = (layer == 0) ? (ph < Tn) : (ph >= 1);

    // --- stage h-half (and L1's x-half) from coherence point, unpack ---
    if (act) {
      const unsigned* h1p = hex1 + ((ph - 1) & 1) * 8192 + srow * 512 + kseg;
      if (layer == 0) {
        stage_unpack_sc1(h1p, Xh, Xl, srow * XSTR + 512 + kseg);
      } else {
        stage_unpack_sc1(h1p, Xh, Xl, srow * XSTR + kseg);  // x = h1[t]
        stage_unpack_sc1(hex2 + (ph & 1) * 8192 + srow * 512 + kseg,
                         Xh, Xl, srow * XSTR + 512 + kseg);
      }
    }
    __syncthreads();

    // --- MFMA dot: 12 mfma (4 k-iters x 3 split products) per wave ---
    if (act) {
      f32x4 acc = {0.f, 0.f, 0.f, 0.f};
#pragma unroll
      for (int it = 0; it < 4; ++it) {
        const int kb = w * 128 + it * 32 + g8;
        const short8 ahf = *(const short8*)&Xh[m * XSTR + kb];
        const short8 alf = *(const short8*)&Xl[m * XSTR + kb];
        const short8 bhf = *(const short8*)&Wh[m * XSTR + kb];
        const short8 blf = *(const short8*)&Wlo[m * XSTR + kb];
        acc = __builtin_amdgcn_mfma_f32_16x16x32_bf16(ahf, bhf, acc, 0, 0, 0);
        acc = __builtin_amdgcn_mfma_f32_16x16x32_bf16(ahf, blf, acc, 0, 0, 0);
        acc = __builtin_amdgcn_mfma_f32_16x16x32_bf16(alf, bhf, acc, 0, 0, 0);
      }
      // C/D layout: col = lane&15, row = (lane>>4)*4 + reg (m89-verified)
      const int r0 = (lane >> 4) * 4;
#pragma unroll
      for (int r = 0; r < 4; ++r)
        red[w * 272 + (r0 + r) * 17 + m] = acc[r];
    }
    __syncthreads();

    // --- reduce 8 wave partials ---
    if (act && tid < 256) {
      const int b = tid >> 4, c = tid & 15;
      float s = 0.f;
#pragma unroll
      for (int ww = 0; ww < 8; ++ww) s += red[ww * 272 + b * 17 + c];
      gates[tid] = s;
    }
    __syncthreads();

    // --- activations + packed h publish ---
    if (act && tid < 64) {
      const int b = tid >> 2, j = tid & 3;
      const float gi = gates[b * 16 + j] + bb0;
      const float gf = gates[b * 16 + 4 + j] + bb1;
      const float gg = gates[b * 16 + 8 + j] + bb2;
      const float go = gates[b * 16 + 12 + j] + bb3;
      const float si = 1.f / (1.f + expf(-gi));
      const float sf = 1.f / (1.f + expf(-gf));
      const float tg = tanhf(gg);
      const float so = 1.f / (1.f + expf(-go));
      const float cn = sf * cst[tid] + si * tg;
      cst[tid] = cn;
      const float hn = so * tanhf(cn);
      const unsigned short hh = f2bf(hn);
      const unsigned short hl = f2bf(hn - bf2f(hh));
      const unsigned pk = ((unsigned)hh << 16) | (unsigned)hl;
      unsigned* hdst = (layer == 0)
          ? hex1 + (ph & 1) * 8192 + b * 512 + (u0 + j)
          : hex2 + ((ph - 1) & 1) * 8192 + b * 512 + (u0 + j);
      flagst(hdst, pk);  // sc1 -> coherence point
      if (layer == 1) {
        const size_t r = (size_t)(ph - 1) * 16 + b;
        Ah[r * Hn + u0 + j] = hh;
        Al[r * Hn + u0 + j] = hl;
      }
    }
    __syncthreads();  // drains h stores (vmcnt) block-wide

    if (tid == 0) flagst(myslot, target);

    // --- overlap the wait: L0 pre-stages embed x for the next step ---
    if (layer == 0 && (ph + 1) < Tn) {
      const int tok = tokens[srow * Tn + (ph + 1)];
      stage_f32(embed + (size_t)tok * Hn + kseg, Xh, Xl, srow * XSTR + kseg);
    }
    if (tid < 256) {
      while (pollld(pollslot) < target) __builtin_amdgcn_s_sleep(2);
    }
    __syncthreads();
  }
}

// ---------------- projection GEMM: out[b][t][v] = H2 @ Wout + bout ----------
__global__ __launch_bounds__(256) void proj_gemm(
    const unsigned short* __restrict__ Ah_, const unsigned short* __restrict__ Al_,
    const unsigned short* __restrict__ Bh_, const unsigned short* __restrict__ Bl_,
    const float* __restrict__ bout, float* __restrict__ out) {
  __shared__ unsigned short sAh[128 * PSTR], sAl[128 * PSTR], sBh[128 * PSTR], sBl[128 * PSTR];
  const int tid = threadIdx.x;
  const int n0 = blockIdx.x * 128;
  const int m0 = blockIdx.y * 128;
  const int lane = tid & 63, w = tid >> 6;
  const int wm = (w & 1) * 64, wn = (w >> 1) * 64;

  f32x4 acc[4][4];
#pragma unroll
  for (int i = 0; i < 4; ++i)
#pragma unroll
    for (int j = 0; j < 4; ++j) acc[i][j] = (f32x4){0.f, 0.f, 0.f, 0.f};

  for (int kt = 0; kt < 16; ++kt) {
    const int k0 = kt * 32;
    __syncthreads();
#pragma unroll
    for (int i = 0; i < 8; ++i) {
      const int chunk = ((i & 1) << 8) + tid;
      const int mrow = chunk >> 2;
      const int kc = chunk & 3;
      const int tsel = i >> 1;
      const unsigned short* gsrc =
          (tsel == 0) ? Ah_ + (size_t)(m0 + mrow) * Hn + k0 + kc * 8 :
          (tsel == 1) ? Al_ + (size_t)(m0 + mrow) * Hn + k0 + kc * 8 :
          (tsel == 2) ? Bh_ + (size_t)(n0 + mrow) * Hn + k0 + kc * 8 :
                        Bl_ + (size_t)(n0 + mrow) * Hn + k0 + kc * 8;
      unsigned short* ldst = (tsel == 0) ? sAh : (tsel == 1) ? sAl : (tsel == 2) ? sBh : sBl;
      *(i32x4*)&ldst[mrow * PSTR + kc * 8] = *(const i32x4*)gsrc;
    }
    __syncthreads();

    short8 fah[4], fal[4], fbh[4], fbl[4];
    const int rlo = lane & 15, kg = (lane >> 4) * 8;
#pragma unroll
    for (int f = 0; f < 4; ++f) {
      fah[f] = *(const short8*)&sAh[(wm + f * 16 + rlo) * PSTR + kg];
      fal[f] = *(const short8*)&sAl[(wm + f * 16 + rlo) * PSTR + kg];
      fbh[f] = *(const short8*)&sBh[(wn + f * 16 + rlo) * PSTR + kg];
      fbl[f] = *(const short8*)&sBl[(wn + f * 16 + rlo) * PSTR + kg];
    }
#pragma unroll
    for (int i = 0; i < 4; ++i)
#pragma unroll
      for (int j = 0; j < 4; ++j) {
        acc[i][j] = __builtin_amdgcn_mfma_f32_16x16x32_bf16(fah[i], fbh[j], acc[i][j], 0, 0, 0);
        acc[i][j] = __builtin_amdgcn_mfma_f32_16x16x32_bf16(fah[i], fbl[j], acc[i][j], 0, 0, 0);
        acc[i][j] = __builtin_amdgcn_mfma_f32_16x16x32_bf16(fal[i], fbh[j], acc[i][j], 0, 0, 0);
      }
  }

#pragma unroll
  for (int j = 0; j < 4; ++j) {
    const int n = n0 + wn + j * 16 + (lane & 15);
    const float bv = bout[n];
#pragma unroll
    for (int i = 0; i < 4; ++i) {
#pragma unroll
      for (int r = 0; r < 4; ++r) {
        const int m = m0 + wm + i * 16 + ((lane >> 4) * 4) + r;
        out[(size_t)(m & 15) * ((size_t)Tn * Vn) + (size_t)(m >> 4) * Vn + n] =
            acc[i][j][r] + bv;
      }
    }
  }
}

extern "C" void kernel_launch(void* const* d_in, const int* in_sizes, int n_in,
                              void* d_out, int out_size, void* d_ws, size_t ws_size,
                              hipStream_t stream) {
  const int*   tokens = (const int*)d_in[0];
  const float* embed  = (const float*)d_in[1];
  const float* W      = (const float*)d_in[2];
  const float* bias   = (const float*)d_in[3];
  const float* Wout   = (const float*)d_in[4];
  const float* bout   = (const float*)d_in[5];
  float* out = (float*)d_out;

  char* ws = (char*)d_ws;
  unsigned* arr  = (unsigned*)ws;                      // 256 * 2048 B
  unsigned* hex1 = (unsigned*)(ws + 524288);           // 2 slots * 16*512 u32
  unsigned* hex2 = (unsigned*)(ws + 524288 + 65536);   // 2 slots * 16*512 u32
  unsigned short* Ah  = (unsigned short*)(ws + 655360);
  unsigned short* Al  = Ah + (size_t)8192 * 512;
  unsigned short* BhT = Al + (size_t)8192 * 512;
  unsigned short* BlT = BhT + (size_t)32000 * 512;
  // total ws use: ~83 MB

  // zero barrier slots + packed h exchange buffers (fresh every launch)
  hipMemsetAsync(d_ws, 0, 655360, stream);

  wout_convert<<<dim3(500, 8), 256, 0, stream>>>(Wout, BhT, BlT);

  const size_t ldsbytes = (size_t)(4 * 16 * XSTR) * 2 +
                          (size_t)(8 * 272 + 256 + 64) * 4;  // 142080
  (void)hipFuncSetAttribute((const void*)lstm_scan,
                            hipFuncAttributeMaxDynamicSharedMemorySize, (int)ldsbytes);
  lstm_scan<<<NBLK, 512, ldsbytes, stream>>>(tokens, embed, W, bias,
                                             hex1, hex2, Ah, Al, arr);

  proj_gemm<<<dim3(250, 64), 256, 0, stream>>>(Ah, Al, BhT, BlT, bout, out);
}